// Round 8
// baseline (169.979 us; speedup 1.0000x reference)
//
#include <hip/hip_runtime.h>

// Problem constants
#define BB    4
#define CIN   256
#define NPIX  4096     // 64*64
#define COUT  512
#define KD    256      // KEY_DIM = VAL_DIM
#define HEADS 8
#define NQ    1024     // 32*32
#define NK    4096
#define EPSV  1e-5f
// 1/sqrt(32) * log2(e): scores come out in base-2 so attn uses v_exp_f32
// directly (no v_mul per element).
#define QSCALE (0.17677669529663687f * 1.4426950408889634f)

using short8 = __attribute__((ext_vector_type(8))) short;
using f32x4  = __attribute__((ext_vector_type(4))) float;

__device__ __forceinline__ float b2f(unsigned u){ return __uint_as_float(u << 16); }
__device__ __forceinline__ unsigned short f2b(float f){
  unsigned u = __float_as_uint(f);
  return (unsigned short)((u + 0x7fffu + ((u >> 16) & 1u)) >> 16);  // RNE
}
__device__ __forceinline__ float bnrelu(float xv, float inv, float mu, float bt){
  return fmaxf((xv - mu) * inv + bt, 0.0f);
}
// pack two fp32 -> bf16x2 (round-half-up): 2 add + 1 v_perm
__device__ __forceinline__ unsigned pkbf(float lo, float hi){
  unsigned a = __float_as_uint(lo) + 0x8000u;
  unsigned b = __float_as_uint(hi) + 0x8000u;
  return __builtin_amdgcn_perm(b, a, 0x07060302u);  // [hi16(b)|hi16(a)]
}
// pack two fp32 -> bf16x2 via single HW instruction (RNE)
__device__ __forceinline__ unsigned cvtpk(float lo, float hi){
  unsigned r;
  asm("v_cvt_pk_bf16_f32 %0, %1, %2" : "=v"(r) : "v"(lo), "v"(hi));
  return r;
}

#define WF_K  2560
#define WF_E  (512*2560)

// ---------------------------------------------------------------------------
// prep_all = prep_w3 (blk<832) + prep_h (blk>=832). (verified, unchanged)
// ---------------------------------------------------------------------------
__global__ __launch_bounds__(256) void prep_all(
    const float* __restrict__ x, const float* __restrict__ gam,
    const float* __restrict__ bet, const float* __restrict__ mea,
    const float* __restrict__ var,
    const float* __restrict__ wsh, const float* __restrict__ wq,
    const float* __restrict__ wk,  const float* __restrict__ wv,
    const float* __restrict__ wo,
    unsigned short* __restrict__ h_t, unsigned short* __restrict__ W2){
  __shared__ unsigned short T[64][264];      // prep_w reuses as float R[2304]
  const int blk = blockIdx.x;
  const int t = threadIdx.x;
  if (blk < 832){
    if (blk < 512){
      float* R = (float*)&T[0][0];
      const float* src = wsh + (size_t)blk * 2304;
      #pragma unroll
      for (int i = 0; i < 9; ++i) R[i * 256 + t] = src[i * 256 + t];
      __syncthreads();
      unsigned short* dst = W2 + (size_t)blk * WF_K;
      #pragma unroll
      for (int i = 0; i < 9; ++i){
        int kp = i * 256 + t;                // k' = tap*256 + ci
        int tap = kp >> 8, ci = kp & 255;
        dst[kp] = f2b(R[ci * 9 + tap]);
      }
    } else if (blk < 704){
      int idx = (blk - 512) * 1024 + t * 4;  // [0, 196608)
      float4 v;
      if (idx < 65536){
        v = *(const float4*)(wq + idx);
        v.x *= QSCALE; v.y *= QSCALE; v.z *= QSCALE; v.w *= QSCALE;
      } else if (idx < 2*65536){ v = *(const float4*)(wk + idx - 65536);
      } else {                   v = *(const float4*)(wv + idx - 2*65536); }
      uint2 pk;
      pk.x = (unsigned)f2b(v.x) | ((unsigned)f2b(v.y) << 16);
      pk.y = (unsigned)f2b(v.z) | ((unsigned)f2b(v.w) << 16);
      *(uint2*)(W2 + WF_E + idx) = pk;
    } else {
      int idx = (blk - 704) * 1024 + t * 4;  // [0, 131072) over wo
      int m = idx >> 8, c = idx & 255;
      float4 v = *(const float4*)(wo + idx);
      uint2 pk;
      pk.x = (unsigned)f2b(v.x) | ((unsigned)f2b(v.y) << 16);
      pk.y = (unsigned)f2b(v.z) | ((unsigned)f2b(v.w) << 16);
      *(uint2*)(W2 + (size_t)m * WF_K + 2304 + c) = pk;
    }
    return;
  }
  // ---- prep_h ----
  const int lin = blk - 832;
  const int b = lin >> 6;
  const int pix0 = (lin & 63) * 64;
  const int w = t >> 6, lane = t & 63;
  for (int cc = 0; cc < 32; ++cc){
    int c0 = cc * 8 + w * 2;
    float i0 = gam[c0]   * rsqrtf(var[c0]   + EPSV), mu0 = mea[c0],   bt0 = bet[c0];
    float i1 = gam[c0+1] * rsqrtf(var[c0+1] + EPSV), mu1 = mea[c0+1], bt1 = bet[c0+1];
    float v0 = bnrelu(x[((size_t)(b*CIN + c0  ))*NPIX + pix0 + lane], i0, mu0, bt0);
    float v1 = bnrelu(x[((size_t)(b*CIN + c0+1))*NPIX + pix0 + lane], i1, mu1, bt1);
    *(unsigned*)&T[lane][c0] = pkbf(v0, v1);
  }
  __syncthreads();
  int p = t >> 2;
  unsigned short* dst = h_t + ((size_t)b * NPIX + pix0 + p) * CIN;
  #pragma unroll
  for (int i = 0; i < 8; ++i){
    int coff = i * 32 + (t & 3) * 8;
    *(uint4*)(dst + coff) = *(const uint4*)&T[p][coff];
  }
}

// ---------------------------------------------------------------------------
// qkv_gemm (BK=64, round-7 verified, unchanged).
// ---------------------------------------------------------------------------
__global__ __launch_bounds__(256) void qkv_gemm(
    const unsigned short* __restrict__ Wkv,   // [wk2;wv2] = [512][256]
    const unsigned short* __restrict__ Wq,    // [256][256]
    const unsigned short* __restrict__ h_t,
    unsigned short* __restrict__ ktg,
    unsigned short* __restrict__ vtg,
    unsigned short* __restrict__ qt){
  __shared__ unsigned short As[64][72];
  __shared__ unsigned short Bs[128][72];
  const int b = blockIdx.z;
  const int t = threadIdx.x;
  const int w = t >> 6, lane = t & 63, col = lane & 15, quad = lane >> 4;
  const int wm = w & 1, wn = w >> 1;

  if (blockIdx.y < 8){
    // ---- kv_gemm (BK=64) ----
    const int m0 = blockIdx.y * 64;
    const bool isv = m0 >= 256;
    const int n0 = blockIdx.x * 128;
    f32x4 acc[2][4];
    #pragma unroll
    for (int i = 0; i < 2; ++i)
      #pragma unroll
      for (int j = 0; j < 4; ++j) acc[i][j] = (f32x4){0.f,0.f,0.f,0.f};
    const int am = t >> 2, ak = (t & 3) * 8;
    const int bn = t >> 1, bkh = (t & 1) * 16;
    const size_t browbase = ((size_t)b * NPIX + (n0 + bn)) * CIN;

    uint4 av0 = *(const uint4*)(Wkv + (size_t)(m0 + am) * 256 + ak);
    uint4 av1 = *(const uint4*)(Wkv + (size_t)(m0 + am) * 256 + 32 + ak);
    uint4 bv0 = *(const uint4*)(h_t + browbase + bkh);
    uint4 bv1 = *(const uint4*)(h_t + browbase + bkh + 8);
    uint4 bv2 = *(const uint4*)(h_t + browbase + 32 + bkh);
    uint4 bv3 = *(const uint4*)(h_t + browbase + 32 + bkh + 8);

    for (int k0 = 0; k0 < 256; k0 += 64){
      *(uint4*)&As[am][ak]           = av0;
      *(uint4*)&As[am][32 + ak]      = av1;
      *(uint4*)&Bs[bn][bkh]          = bv0;
      *(uint4*)&Bs[bn][bkh + 8]      = bv1;
      *(uint4*)&Bs[bn][32 + bkh]     = bv2;
      *(uint4*)&Bs[bn][32 + bkh + 8] = bv3;
      __syncthreads();
      if (k0 + 64 < 256){                     // prefetch next chunk
        av0 = *(const uint4*)(Wkv + (size_t)(m0 + am) * 256 + k0 + 64 + ak);
        av1 = *(const uint4*)(Wkv + (size_t)(m0 + am) * 256 + k0 + 96 + ak);
        bv0 = *(const uint4*)(h_t + browbase + k0 + 64 + bkh);
        bv1 = *(const uint4*)(h_t + browbase + k0 + 64 + bkh + 8);
        bv2 = *(const uint4*)(h_t + browbase + k0 + 96 + bkh);
        bv3 = *(const uint4*)(h_t + browbase + k0 + 96 + bkh + 8);
      }
      #pragma unroll
      for (int h = 0; h < 2; ++h){
        short8 af[2], bf[4];
        af[0] = *(const short8*)&As[wm * 32 +      col][h * 32 + quad * 8];
        af[1] = *(const short8*)&As[wm * 32 + 16 + col][h * 32 + quad * 8];
        #pragma unroll
        for (int j = 0; j < 4; ++j)
          bf[j] = *(const short8*)&Bs[wn * 64 + j * 16 + col][h * 32 + quad * 8];
        if (!isv){
          #pragma unroll
          for (int i = 0; i < 2; ++i)
            #pragma unroll
            for (int j = 0; j < 4; ++j)
              acc[i][j] = __builtin_amdgcn_mfma_f32_16x16x32_bf16(af[i], bf[j], acc[i][j], 0, 0, 0);
        } else {
          #pragma unroll
          for (int i = 0; i < 2; ++i)
            #pragma unroll
            for (int j = 0; j < 4; ++j)
              acc[i][j] = __builtin_amdgcn_mfma_f32_16x16x32_bf16(bf[j], af[i], acc[i][j], 0, 0, 0);
        }
      }
      __syncthreads();
    }

    if (!isv){
      int head = (m0 + wm * 32) >> 5;
      #pragma unroll
      for (int i = 0; i < 2; ++i){
        int d0 = i * 16 + quad * 4;
        #pragma unroll
        for (int j = 0; j < 4; ++j){
          int n = n0 + wn * 64 + j * 16 + col;
          uint2 pk;
          pk.x = pkbf(acc[i][j][0], acc[i][j][1]);
          pk.y = pkbf(acc[i][j][2], acc[i][j][3]);
          *(uint2*)(ktg + ((size_t)(b * HEADS + head) * NK + n) * 32 + d0) = pk;
        }
      }
    } else {
      int head = ((m0 - 256) + wm * 32) >> 5;
      #pragma unroll
      for (int i = 0; i < 2; ++i){
        int d = i * 16 + col;
        #pragma unroll
        for (int j = 0; j < 4; ++j){
          int nb = n0 + wn * 64 + j * 16 + quad * 4;
          size_t addr = (((size_t)(b * HEADS + head) * 128 + (nb >> 5)) * 32 + d) * 32 + (nb & 31);
          uint2 pk;
          pk.x = pkbf(acc[i][j][0], acc[i][j][1]);
          pk.y = pkbf(acc[i][j][2], acc[i][j][3]);
          *(uint2*)(vtg + addr) = pk;
        }
      }
    }
    return;
  }

  // ---- q_gemm (BK=64) ----
  const int lin = (blockIdx.y - 8) * 32 + blockIdx.x;   // [0,64)
  const int m0 = (lin >> 4) * 64;
  const int n0 = (lin & 15) * 64;
  f32x4 acc[2][2];
  #pragma unroll
  for (int i = 0; i < 2; ++i)
    #pragma unroll
    for (int j = 0; j < 2; ++j) acc[i][j] = (f32x4){0.f,0.f,0.f,0.f};
  const int am = t >> 2, ak = (t & 3) * 8;
  const int bn = t >> 2, bk = (t & 3) * 8;
  int n = n0 + bn;
  const size_t browbase = ((size_t)b * NPIX + (((n >> 5) << 7) + ((n & 31) << 1))) * CIN;

  uint4 av0 = *(const uint4*)(Wq + (size_t)(m0 + am) * 256 + ak);
  uint4 av1 = *(const uint4*)(Wq + (size_t)(m0 + am) * 256 + 32 + ak);
  uint4 bv0 = *(const uint4*)(h_t + browbase + bk);
  uint4 bv1 = *(const uint4*)(h_t + browbase + 32 + bk);

  for (int k0 = 0; k0 < 256; k0 += 64){
    *(uint4*)&As[am][ak]      = av0;
    *(uint4*)&As[am][32 + ak] = av1;
    *(uint4*)&Bs[bn][bk]      = bv0;
    *(uint4*)&Bs[bn][32 + bk] = bv1;
    __syncthreads();
    if (k0 + 64 < 256){
      av0 = *(const uint4*)(Wq + (size_t)(m0 + am) * 256 + k0 + 64 + ak);
      av1 = *(const uint4*)(Wq + (size_t)(m0 + am) * 256 + k0 + 96 + ak);
      bv0 = *(const uint4*)(h_t + browbase + k0 + 64 + bk);
      bv1 = *(const uint4*)(h_t + browbase + k0 + 96 + bk);
    }
    #pragma unroll
    for (int h = 0; h < 2; ++h){
      short8 af[2], bf[2];
      af[0] = *(const short8*)&As[wm * 32 +      col][h * 32 + quad * 8];
      af[1] = *(const short8*)&As[wm * 32 + 16 + col][h * 32 + quad * 8];
      bf[0] = *(const short8*)&Bs[wn * 32 +      col][h * 32 + quad * 8];
      bf[1] = *(const short8*)&Bs[wn * 32 + 16 + col][h * 32 + quad * 8];
      #pragma unroll
      for (int i = 0; i < 2; ++i)
        #pragma unroll
        for (int j = 0; j < 2; ++j)
          acc[i][j] = __builtin_amdgcn_mfma_f32_16x16x32_bf16(af[i], bf[j], acc[i][j], 0, 0, 0);
    }
    __syncthreads();
  }

  int head = (m0 + wm * 32) >> 5;
  #pragma unroll
  for (int i = 0; i < 2; ++i){
    int d0 = i * 16 + quad * 4;
    #pragma unroll
    for (int j = 0; j < 2; ++j){
      int nn = n0 + wn * 32 + j * 16 + col;
      uint2 pk;
      pk.x = pkbf(acc[i][j][0], acc[i][j][1]);
      pk.y = pkbf(acc[i][j][2], acc[i][j][3]);
      *(uint2*)(qt + ((size_t)(b * HEADS + head) * NQ + nn) * 32 + d0) = pk;
    }
  }
}

// ---------------------------------------------------------------------------
// Fused shortcut+wo GEMM, 64x64 tiles, BK=64 (round-6 verified, unchanged).
// ---------------------------------------------------------------------------
__global__ __launch_bounds__(256) void scwo_gemm(
    const unsigned short* __restrict__ Wf,    // [512][2560]
    const unsigned short* __restrict__ h_t,
    const unsigned short* __restrict__ aot,   // [b][1024][256]
    float* __restrict__ outf){
  const int b  = blockIdx.z;
  const int m0 = blockIdx.y * 64;
  const int n0 = blockIdx.x * 64;
  const int t  = threadIdx.x;
  const int w = t >> 6, lane = t & 63, col = lane & 15, quad = lane >> 4;
  const int wm = w & 1, wn = w >> 1;
  __shared__ unsigned short As[64][72];
  __shared__ unsigned short Bs[64][72];
  f32x4 acc[2][2];
  #pragma unroll
  for (int i = 0; i < 2; ++i)
    #pragma unroll
    for (int j = 0; j < 2; ++j) acc[i][j] = (f32x4){0.f,0.f,0.f,0.f};
  const int am = t >> 2, ak = (t & 3) * 8;
  const int bn = t >> 2, bk = (t & 3) * 8;
  const int n = n0 + bn;
  const int oy = n >> 5, ox = n & 31;
  const size_t aobase = ((size_t)b * NQ + n) * KD;

  auto loadB = [&](int k0) -> uint4 {
    if (k0 < 2304){
      int tap = k0 >> 8;                     // uniform per 32-chunk
      int ky = tap / 3, kx = tap - ky * 3;
      int iy = 2 * oy + ky - 1, ix = 2 * ox + kx - 1;
      if (((unsigned)iy < 64u) && ((unsigned)ix < 64u))
        return *(const uint4*)(h_t + ((size_t)b * NPIX + iy * 64 + ix) * CIN + (k0 & 255) + bk);
      return make_uint4(0,0,0,0);            // conv zero-pad
    }
    return *(const uint4*)(aot + aobase + (k0 - 2304) + bk);
  };

  uint4 av0 = *(const uint4*)(Wf + (size_t)(m0 + am) * WF_K + ak);
  uint4 av1 = *(const uint4*)(Wf + (size_t)(m0 + am) * WF_K + 32 + ak);
  uint4 bv0 = loadB(0);
  uint4 bv1 = loadB(32);

  for (int k0 = 0; k0 < WF_K; k0 += 64){
    *(uint4*)&As[am][ak]      = av0;
    *(uint4*)&As[am][32 + ak] = av1;
    *(uint4*)&Bs[bn][bk]      = bv0;
    *(uint4*)&Bs[bn][32 + bk] = bv1;
    __syncthreads();
    if (k0 + 64 < WF_K){
      av0 = *(const uint4*)(Wf + (size_t)(m0 + am) * WF_K + k0 + 64 + ak);
      av1 = *(const uint4*)(Wf + (size_t)(m0 + am) * WF_K + k0 + 96 + ak);
      bv0 = loadB(k0 + 64);
      bv1 = loadB(k0 + 96);
    }
    #pragma unroll
    for (int h = 0; h < 2; ++h){
      short8 af[2], bf[2];
      af[0] = *(const short8*)&As[wm * 32 +      col][h * 32 + quad * 8];
      af[1] = *(const short8*)&As[wm * 32 + 16 + col][h * 32 + quad * 8];
      bf[0] = *(const short8*)&Bs[wn * 32 +      col][h * 32 + quad * 8];
      bf[1] = *(const short8*)&Bs[wn * 32 + 16 + col][h * 32 + quad * 8];
      #pragma unroll
      for (int i = 0; i < 2; ++i)
        #pragma unroll
        for (int j = 0; j < 2; ++j)
          acc[i][j] = __builtin_amdgcn_mfma_f32_16x16x32_bf16(bf[j], af[i], acc[i][j], 0, 0, 0);
    }
    __syncthreads();
  }

  #pragma unroll
  for (int i = 0; i < 2; ++i){
    int co = m0 + wm * 32 + i * 16 + col;
    #pragma unroll
    for (int j = 0; j < 2; ++j){
      int nb = n0 + wn * 32 + j * 16 + quad * 4;
      float4 o;
      o.x = acc[i][j][0]; o.y = acc[i][j][1];
      o.z = acc[i][j][2]; o.w = acc[i][j][3];
      *(float4*)(outf + ((size_t)(b * COUT + co)) * NQ + nb) = o;
    }
  }
}

// ---------------------------------------------------------------------------
// attn11: LDS-read-halving via 2 q-tiles per wave, SAME 512-thread/8-wave/
// grid-256 envelope as the verified attn9c. Wave w: q-pair p = w&3 (tiles
// 2p, 2p+1 of this q-group) x key-half kh = w>>2 (keys kh*2048..+2047).
// Each K/V fragment is read from LDS once and feeds BOTH q-tiles -> per-CU
// ds_read count halves (the measured bottleneck; round-7 barrier halving
// was null, confirming LDS-read-bound).
// Staging: attn9b role formulas byte-identical, one entry per half; half h
// adds h*65536 shorts on the global side (K: 2048 keys*32; V: 64 chunks*1024)
// and h*4096 on the LDS side. Step = 64 keys per half (both halves advance
// together); 32 steps; KV[2][8192] shorts = 32 KB (same as attn9c).
// 2-way merge: kh=1 waves park (O,l) in LDS (aliased onto KV after the final
// barrier -- no one reads KV anymore), kh=0 waves add + normalize + store.
// ---------------------------------------------------------------------------
__global__ __launch_bounds__(512) void attn11(
    const unsigned short* __restrict__ qt,    // [bh][1024][32] (pre-scaled)
    const unsigned short* __restrict__ ktg,   // [bh][4096][32]
    const unsigned short* __restrict__ vtg,   // [bh][128][32][32] blocked V^T
    unsigned short* __restrict__ aot){        // [b][1024][256]
  __shared__ unsigned short KV[2][8192];      // [buf][half][K 2048 | V 2048]
  const int bid = blockIdx.x;
  const int xcd = bid & 7, idx = bid >> 3;    // 256 blocks
  const int bh = xcd * 4 + (idx & 3);         // 4 bh per XCD
  const int qg = idx >> 2;                    // 0..7 (q-groups of 128)
  const int b = bh >> 3, hd = bh & 7;
  const int t = threadIdx.x;
  const int w = t >> 6, lane = t & 63, col = lane & 15, quad = lane >> 4;
  const int p = w & 3, kh = w >> 2;
  const int qA = (qg * 8 + 2 * p) * 16 + col;   // wave owns tiles 2p, 2p+1
  const int qB = qA + 16;

  short8 qfA = *(const short8*)(qt + ((size_t)bh * NQ + qA) * 32 + quad * 8);
  short8 qfB = *(const short8*)(qt + ((size_t)bh * NQ + qB) * 32 + quad * 8);
  const unsigned short* kb = ktg + (size_t)bh * NK * 32;
  const unsigned short* vb = vtg + (size_t)bh * 128 * 1024;

  // staging: attn9b roles (w<4 -> K entry, w>=4 -> V entry); one entry per
  // half. Step s adds s*2048 shorts; half 1 adds 65536 (global), 4096 (LDS).
  const int sg = (w & 3) >> 1, sf = w & 1;
  const size_t ksrc = (size_t)(32 * sg + 16 * sf + col) * 32 + quad * 8;
  const size_t vsrc = (size_t)sg * 1024 + (size_t)(16 * sf + col) * 32 + quad * 8;
  const unsigned short* sb = (w < 4) ? kb + ksrc : vb + vsrc;
  unsigned short* ddst = &KV[0][w * 512 + lane * 8];   // V waves land at +2048

  f32x4 OA0 = {0.f,0.f,0.f,0.f}, OA1 = {0.f,0.f,0.f,0.f}, lA = {0.f,0.f,0.f,0.f};
  f32x4 OB0 = {0.f,0.f,0.f,0.f}, OB1 = {0.f,0.f,0.f,0.f}, lB = {0.f,0.f,0.f,0.f};
  const short8 ones = {0x3F80,0x3F80,0x3F80,0x3F80,0x3F80,0x3F80,0x3F80,0x3F80};

  *(uint4*)ddst          = *(const uint4*)sb;            // half 0, step 0
  *(uint4*)(ddst + 4096) = *(const uint4*)(sb + 65536);  // half 1, step 0
  __syncthreads();

  for (int s = 0; s < 32; ++s){
    const int cur = s & 1;
    uint4 n1, n2;
    if (s + 1 < 32){                          // issue early: latency hides
      size_t soff = (size_t)(s + 1) * 2048;
      n1 = *(const uint4*)(sb + soff);
      n2 = *(const uint4*)(sb + soff + 65536);
    }
    #pragma unroll
    for (int g = 0; g < 2; ++g){
      const unsigned short* Kp = &KV[cur][kh * 4096 + g * 1024];
      short8 kf0 = *(const short8*)(Kp +       lane * 8);
      short8 kf1 = *(const short8*)(Kp + 512 + lane * 8);
      f32x4 z = {0.f,0.f,0.f,0.f};
      f32x4 sloA = __builtin_amdgcn_mfma_f32_16x16x32_bf16(kf0, qfA, z, 0, 0, 0);
      f32x4 shiA = __builtin_amdgcn_mfma_f32_16x16x32_bf16(kf1, qfA, z, 0, 0, 0);
      f32x4 sloB = __builtin_amdgcn_mfma_f32_16x16x32_bf16(kf0, qfB, z, 0, 0, 0);
      f32x4 shiB = __builtin_amdgcn_mfma_f32_16x16x32_bf16(kf1, qfB, z, 0, 0, 0);

      unsigned xa0 = cvtpk(__builtin_amdgcn_exp2f(sloA[0]), __builtin_amdgcn_exp2f(sloA[1]));
      unsigned xa1 = cvtpk(__builtin_amdgcn_exp2f(sloA[2]), __builtin_amdgcn_exp2f(sloA[3]));
      unsigned ya0 = cvtpk(__builtin_amdgcn_exp2f(shiA[0]), __builtin_amdgcn_exp2f(shiA[1]));
      unsigned ya1 = cvtpk(__builtin_amdgcn_exp2f(shiA[2]), __builtin_amdgcn_exp2f(shiA[3]));
      asm("v_permlane32_swap_b32 %0, %1" : "+v"(xa0), "+v"(ya0));
      asm("v_permlane32_swap_b32 %0, %1" : "+v"(xa1), "+v"(ya1));
      asm("v_permlane16_swap_b32 %0, %1" : "+v"(xa0), "+v"(ya0));
      asm("v_permlane16_swap_b32 %0, %1" : "+v"(xa1), "+v"(ya1));
      unsigned fa[4] = {xa0, xa1, ya0, ya1};
      short8 pfA;
      memcpy(&pfA, fa, 16);

      unsigned xb0 = cvtpk(__builtin_amdgcn_exp2f(sloB[0]), __builtin_amdgcn_exp2f(sloB[1]));
      unsigned xb1 = cvtpk(__builtin_amdgcn_exp2f(sloB[2]), __builtin_amdgcn_exp2f(sloB[3]));
      unsigned yb0 = cvtpk(__builtin_amdgcn_exp2f(shiB[0]), __builtin_amdgcn_exp2f(shiB[1]));
      unsigned yb1 = cvtpk(__builtin_amdgcn_exp2f(shiB[2]), __builtin_amdgcn_exp2f(shiB[3]));
      asm("v_permlane32_swap_b32 %0, %1" : "+v"(xb0), "+v"(yb0));
      asm("v_permlane32_swap_b32 %0, %1" : "+v"(xb1), "+v"(yb1));
      asm("v_permlane16_swap_b32 %0, %1" : "+v"(xb0), "+v"(yb0));
      asm("v_permlane16_swap_b32 %0, %1" : "+v"(xb1), "+v"(yb1));
      unsigned fb[4] = {xb0, xb1, yb0, yb1};
      short8 pfB;
      memcpy(&pfB, fb, 16);

      const unsigned short* Vp = &KV[cur][kh * 4096 + 2048 + g * 1024];
      short8 vf0 = *(const short8*)(Vp +       lane * 8);
      short8 vf1 = *(const short8*)(Vp + 512 + lane * 8);
      OA0 = __builtin_amdgcn_mfma_f32_16x16x32_bf16(vf0, pfA, OA0, 0, 0, 0);
      OA1 = __builtin_amdgcn_mfma_f32_16x16x32_bf16(vf1, pfA, OA1, 0, 0, 0);
      lA  = __builtin_amdgcn_mfma_f32_16x16x32_bf16(ones, pfA, lA, 0, 0, 0);
      OB0 = __builtin_amdgcn_mfma_f32_16x16x32_bf16(vf0, pfB, OB0, 0, 0, 0);
      OB1 = __builtin_amdgcn_mfma_f32_16x16x32_bf16(vf1, pfB, OB1, 0, 0, 0);
      lB  = __builtin_amdgcn_mfma_f32_16x16x32_bf16(ones, pfB, lB, 0, 0, 0);
    }
    if (s + 1 < 32){
      *(uint4*)(ddst + (size_t)(cur ^ 1) * 8192)        = n1;   // write-late
      *(uint4*)(ddst + 4096 + (size_t)(cur ^ 1) * 8192) = n2;
    }
    __syncthreads();   // all waves done reading cur; next buf visible
  }

  // ---- 2-way merge (kh=1 partial -> LDS, aliased onto KV; kh=0 finishes).
  // Final loop iteration ended with a barrier, so KV is dead here.
  float* M = (float*)&KV[0][0];   // [4 pairs][64 lanes][24 floats] = 24 KB
  if (kh == 1){
    float* dst = M + ((size_t)p * 64 + lane) * 24;
    *(f32x4*)(dst +  0) = OA0;
    *(f32x4*)(dst +  4) = OA1;
    *(f32x4*)(dst +  8) = OB0;
    *(f32x4*)(dst + 12) = OB1;
    dst[16] = lA[0];
    dst[17] = lB[0];
  }
  __syncthreads();
  if (kh == 0){
    const float* src = M + ((size_t)p * 64 + lane) * 24;
    {
      float inv = 1.0f / (lA[0] + src[16]);
      unsigned short* dst = aot + ((size_t)(b * NQ + qA)) * KD + hd * 32;
      uint2 pk;
      pk.x = pkbf((OA0[0] + src[0]) * inv, (OA0[1] + src[1]) * inv);
      pk.y = pkbf((OA0[2] + src[2]) * inv, (OA0[3] + src[3]) * inv);
      *(uint2*)(dst + quad * 4) = pk;
      pk.x = pkbf((OA1[0] + src[4]) * inv, (OA1[1] + src[5]) * inv);
      pk.y = pkbf((OA1[2] + src[6]) * inv, (OA1[3] + src[7]) * inv);
      *(uint2*)(dst + 16 + quad * 4) = pk;
    }
    {
      float inv = 1.0f / (lB[0] + src[17]);
      unsigned short* dst = aot + ((size_t)(b * NQ + qB)) * KD + hd * 32;
      uint2 pk;
      pk.x = pkbf((OB0[0] + src[8])  * inv, (OB0[1] + src[9])  * inv);
      pk.y = pkbf((OB0[2] + src[10]) * inv, (OB0[3] + src[11]) * inv);
      *(uint2*)(dst + quad * 4) = pk;
      pk.x = pkbf((OB1[0] + src[12]) * inv, (OB1[1] + src[13]) * inv);
      pk.y = pkbf((OB1[2] + src[14]) * inv, (OB1[3] + src[15]) * inv);
      *(uint2*)(dst + 16 + quad * 4) = pk;
    }
  }
}

// ---------------------------------------------------------------------------
extern "C" void kernel_launch(void* const* d_in, const int* in_sizes, int n_in,
                              void* d_out, int out_size, void* d_ws, size_t ws_size,
                              hipStream_t stream){
  const float* x   = (const float*)d_in[0];
  const float* bg  = (const float*)d_in[1];
  const float* bbt = (const float*)d_in[2];
  const float* bm  = (const float*)d_in[3];
  const float* bv  = (const float*)d_in[4];
  const float* wsh = (const float*)d_in[5];
  const float* wq  = (const float*)d_in[6];
  const float* wk  = (const float*)d_in[7];
  const float* wvv = (const float*)d_in[8];
  const float* wo  = (const float*)d_in[9];
  float* out = (float*)d_out;                 // fp32 output

  // workspace (bf16), full 4-batch K/V: 32.4 MB
  unsigned short* h_t = (unsigned short*)d_ws;                 // 4*4096*256
  unsigned short* W2  = h_t + (size_t)BB * NPIX * CIN;         // 1,507,328
  unsigned short* qt  = W2  + (WF_E + 3*65536);                // 4*8*1024*32
  unsigned short* aot = qt  + (size_t)BB * HEADS * NQ * 32;    // 4*1024*256
  unsigned short* ktg = aot + (size_t)BB * NQ * KD;            // 4*8*4096*32
  unsigned short* vtg = ktg + (size_t)BB * HEADS * NK * 32;    // 4*8*128*1024
  size_t need = ((size_t)(vtg + (size_t)BB * HEADS * 32 * NK - h_t)) * 2;
  if (ws_size < need) return;

  unsigned short* Wf   = W2;                   // [512][2560] = wsh|wo fused
  unsigned short* wq2  = W2 + WF_E;
  unsigned short* wkv2 = wq2 + 65536;          // [wk2;wv2] = [512][256]

  prep_all<<<dim3(1088), dim3(256), 0, stream>>>(x, bg, bbt, bm, bv,
                                                 wsh, wq, wk, wvv, wo, h_t, W2);
  qkv_gemm<<<dim3(32, 10, 4), dim3(256), 0, stream>>>(wkv2, wq2, h_t, ktg, vtg, qt);
  attn11<<<dim3(256), dim3(512), 0, stream>>>(qt, ktg, vtg, aot);
  scwo_gemm<<<dim3(16, 8, 4), dim3(256), 0, stream>>>(Wf, h_t, aot, out);
}

// Round 9
// 164.741 us; speedup vs baseline: 1.0318x; 1.0318x over previous
//
#include <hip/hip_runtime.h>

// Problem constants
#define BB    4
#define CIN   256
#define NPIX  4096     // 64*64
#define COUT  512
#define KD    256      // KEY_DIM = VAL_DIM
#define HEADS 8
#define NQ    1024     // 32*32
#define NK    4096
#define EPSV  1e-5f
// 1/sqrt(32) * log2(e): scores come out in base-2 so attn uses v_exp_f32
// directly (no v_mul per element).
#define QSCALE (0.17677669529663687f * 1.4426950408889634f)

using short8 = __attribute__((ext_vector_type(8))) short;
using f32x4  = __attribute__((ext_vector_type(4))) float;

__device__ __forceinline__ float b2f(unsigned u){ return __uint_as_float(u << 16); }
__device__ __forceinline__ unsigned short f2b(float f){
  unsigned u = __float_as_uint(f);
  return (unsigned short)((u + 0x7fffu + ((u >> 16) & 1u)) >> 16);  // RNE
}
__device__ __forceinline__ float bnrelu(float xv, float inv, float mu, float bt){
  return fmaxf((xv - mu) * inv + bt, 0.0f);
}
// pack two fp32 -> bf16x2 (round-half-up): 2 add + 1 v_perm
__device__ __forceinline__ unsigned pkbf(float lo, float hi){
  unsigned a = __float_as_uint(lo) + 0x8000u;
  unsigned b = __float_as_uint(hi) + 0x8000u;
  return __builtin_amdgcn_perm(b, a, 0x07060302u);  // [hi16(b)|hi16(a)]
}
// pack two fp32 -> bf16x2 via single HW instruction (RNE)
__device__ __forceinline__ unsigned cvtpk(float lo, float hi){
  unsigned r;
  asm("v_cvt_pk_bf16_f32 %0, %1, %2" : "=v"(r) : "v"(lo), "v"(hi));
  return r;
}

#define WF_K  2560
#define WF_E  (512*2560)

// ---------------------------------------------------------------------------
// prep_all = prep_w3 (blk<832) + prep_h (blk>=832). (verified, unchanged)
// ---------------------------------------------------------------------------
__global__ __launch_bounds__(256) void prep_all(
    const float* __restrict__ x, const float* __restrict__ gam,
    const float* __restrict__ bet, const float* __restrict__ mea,
    const float* __restrict__ var,
    const float* __restrict__ wsh, const float* __restrict__ wq,
    const float* __restrict__ wk,  const float* __restrict__ wv,
    const float* __restrict__ wo,
    unsigned short* __restrict__ h_t, unsigned short* __restrict__ W2){
  __shared__ unsigned short T[64][264];      // prep_w reuses as float R[2304]
  const int blk = blockIdx.x;
  const int t = threadIdx.x;
  if (blk < 832){
    if (blk < 512){
      float* R = (float*)&T[0][0];
      const float* src = wsh + (size_t)blk * 2304;
      #pragma unroll
      for (int i = 0; i < 9; ++i) R[i * 256 + t] = src[i * 256 + t];
      __syncthreads();
      unsigned short* dst = W2 + (size_t)blk * WF_K;
      #pragma unroll
      for (int i = 0; i < 9; ++i){
        int kp = i * 256 + t;                // k' = tap*256 + ci
        int tap = kp >> 8, ci = kp & 255;
        dst[kp] = f2b(R[ci * 9 + tap]);
      }
    } else if (blk < 704){
      int idx = (blk - 512) * 1024 + t * 4;  // [0, 196608)
      float4 v;
      if (idx < 65536){
        v = *(const float4*)(wq + idx);
        v.x *= QSCALE; v.y *= QSCALE; v.z *= QSCALE; v.w *= QSCALE;
      } else if (idx < 2*65536){ v = *(const float4*)(wk + idx - 65536);
      } else {                   v = *(const float4*)(wv + idx - 2*65536); }
      uint2 pk;
      pk.x = (unsigned)f2b(v.x) | ((unsigned)f2b(v.y) << 16);
      pk.y = (unsigned)f2b(v.z) | ((unsigned)f2b(v.w) << 16);
      *(uint2*)(W2 + WF_E + idx) = pk;
    } else {
      int idx = (blk - 704) * 1024 + t * 4;  // [0, 131072) over wo
      int m = idx >> 8, c = idx & 255;
      float4 v = *(const float4*)(wo + idx);
      uint2 pk;
      pk.x = (unsigned)f2b(v.x) | ((unsigned)f2b(v.y) << 16);
      pk.y = (unsigned)f2b(v.z) | ((unsigned)f2b(v.w) << 16);
      *(uint2*)(W2 + (size_t)m * WF_K + 2304 + c) = pk;
    }
    return;
  }
  // ---- prep_h ----
  const int lin = blk - 832;
  const int b = lin >> 6;
  const int pix0 = (lin & 63) * 64;
  const int w = t >> 6, lane = t & 63;
  for (int cc = 0; cc < 32; ++cc){
    int c0 = cc * 8 + w * 2;
    float i0 = gam[c0]   * rsqrtf(var[c0]   + EPSV), mu0 = mea[c0],   bt0 = bet[c0];
    float i1 = gam[c0+1] * rsqrtf(var[c0+1] + EPSV), mu1 = mea[c0+1], bt1 = bet[c0+1];
    float v0 = bnrelu(x[((size_t)(b*CIN + c0  ))*NPIX + pix0 + lane], i0, mu0, bt0);
    float v1 = bnrelu(x[((size_t)(b*CIN + c0+1))*NPIX + pix0 + lane], i1, mu1, bt1);
    *(unsigned*)&T[lane][c0] = pkbf(v0, v1);
  }
  __syncthreads();
  int p = t >> 2;
  unsigned short* dst = h_t + ((size_t)b * NPIX + pix0 + p) * CIN;
  #pragma unroll
  for (int i = 0; i < 8; ++i){
    int coff = i * 32 + (t & 3) * 8;
    *(uint4*)(dst + coff) = *(const uint4*)&T[p][coff];
  }
}

// ---------------------------------------------------------------------------
// qkv_gemm (BK=64, round-7 verified, unchanged).
// ---------------------------------------------------------------------------
__global__ __launch_bounds__(256) void qkv_gemm(
    const unsigned short* __restrict__ Wkv,   // [wk2;wv2] = [512][256]
    const unsigned short* __restrict__ Wq,    // [256][256]
    const unsigned short* __restrict__ h_t,
    unsigned short* __restrict__ ktg,
    unsigned short* __restrict__ vtg,
    unsigned short* __restrict__ qt){
  __shared__ unsigned short As[64][72];
  __shared__ unsigned short Bs[128][72];
  const int b = blockIdx.z;
  const int t = threadIdx.x;
  const int w = t >> 6, lane = t & 63, col = lane & 15, quad = lane >> 4;
  const int wm = w & 1, wn = w >> 1;

  if (blockIdx.y < 8){
    // ---- kv_gemm (BK=64) ----
    const int m0 = blockIdx.y * 64;
    const bool isv = m0 >= 256;
    const int n0 = blockIdx.x * 128;
    f32x4 acc[2][4];
    #pragma unroll
    for (int i = 0; i < 2; ++i)
      #pragma unroll
      for (int j = 0; j < 4; ++j) acc[i][j] = (f32x4){0.f,0.f,0.f,0.f};
    const int am = t >> 2, ak = (t & 3) * 8;
    const int bn = t >> 1, bkh = (t & 1) * 16;
    const size_t browbase = ((size_t)b * NPIX + (n0 + bn)) * CIN;

    uint4 av0 = *(const uint4*)(Wkv + (size_t)(m0 + am) * 256 + ak);
    uint4 av1 = *(const uint4*)(Wkv + (size_t)(m0 + am) * 256 + 32 + ak);
    uint4 bv0 = *(const uint4*)(h_t + browbase + bkh);
    uint4 bv1 = *(const uint4*)(h_t + browbase + bkh + 8);
    uint4 bv2 = *(const uint4*)(h_t + browbase + 32 + bkh);
    uint4 bv3 = *(const uint4*)(h_t + browbase + 32 + bkh + 8);

    for (int k0 = 0; k0 < 256; k0 += 64){
      *(uint4*)&As[am][ak]           = av0;
      *(uint4*)&As[am][32 + ak]      = av1;
      *(uint4*)&Bs[bn][bkh]          = bv0;
      *(uint4*)&Bs[bn][bkh + 8]      = bv1;
      *(uint4*)&Bs[bn][32 + bkh]     = bv2;
      *(uint4*)&Bs[bn][32 + bkh + 8] = bv3;
      __syncthreads();
      if (k0 + 64 < 256){                     // prefetch next chunk
        av0 = *(const uint4*)(Wkv + (size_t)(m0 + am) * 256 + k0 + 64 + ak);
        av1 = *(const uint4*)(Wkv + (size_t)(m0 + am) * 256 + k0 + 96 + ak);
        bv0 = *(const uint4*)(h_t + browbase + k0 + 64 + bkh);
        bv1 = *(const uint4*)(h_t + browbase + k0 + 64 + bkh + 8);
        bv2 = *(const uint4*)(h_t + browbase + k0 + 96 + bkh);
        bv3 = *(const uint4*)(h_t + browbase + k0 + 96 + bkh + 8);
      }
      #pragma unroll
      for (int h = 0; h < 2; ++h){
        short8 af[2], bf[4];
        af[0] = *(const short8*)&As[wm * 32 +      col][h * 32 + quad * 8];
        af[1] = *(const short8*)&As[wm * 32 + 16 + col][h * 32 + quad * 8];
        #pragma unroll
        for (int j = 0; j < 4; ++j)
          bf[j] = *(const short8*)&Bs[wn * 64 + j * 16 + col][h * 32 + quad * 8];
        if (!isv){
          #pragma unroll
          for (int i = 0; i < 2; ++i)
            #pragma unroll
            for (int j = 0; j < 4; ++j)
              acc[i][j] = __builtin_amdgcn_mfma_f32_16x16x32_bf16(af[i], bf[j], acc[i][j], 0, 0, 0);
        } else {
          #pragma unroll
          for (int i = 0; i < 2; ++i)
            #pragma unroll
            for (int j = 0; j < 4; ++j)
              acc[i][j] = __builtin_amdgcn_mfma_f32_16x16x32_bf16(bf[j], af[i], acc[i][j], 0, 0, 0);
        }
      }
      __syncthreads();
    }

    if (!isv){
      int head = (m0 + wm * 32) >> 5;
      #pragma unroll
      for (int i = 0; i < 2; ++i){
        int d0 = i * 16 + quad * 4;
        #pragma unroll
        for (int j = 0; j < 4; ++j){
          int n = n0 + wn * 64 + j * 16 + col;
          uint2 pk;
          pk.x = pkbf(acc[i][j][0], acc[i][j][1]);
          pk.y = pkbf(acc[i][j][2], acc[i][j][3]);
          *(uint2*)(ktg + ((size_t)(b * HEADS + head) * NK + n) * 32 + d0) = pk;
        }
      }
    } else {
      int head = ((m0 - 256) + wm * 32) >> 5;
      #pragma unroll
      for (int i = 0; i < 2; ++i){
        int d = i * 16 + col;
        #pragma unroll
        for (int j = 0; j < 4; ++j){
          int nb = n0 + wn * 64 + j * 16 + quad * 4;
          size_t addr = (((size_t)(b * HEADS + head) * 128 + (nb >> 5)) * 32 + d) * 32 + (nb & 31);
          uint2 pk;
          pk.x = pkbf(acc[i][j][0], acc[i][j][1]);
          pk.y = pkbf(acc[i][j][2], acc[i][j][3]);
          *(uint2*)(vtg + addr) = pk;
        }
      }
    }
    return;
  }

  // ---- q_gemm (BK=64) ----
  const int lin = (blockIdx.y - 8) * 32 + blockIdx.x;   // [0,64)
  const int m0 = (lin >> 4) * 64;
  const int n0 = (lin & 15) * 64;
  f32x4 acc[2][2];
  #pragma unroll
  for (int i = 0; i < 2; ++i)
    #pragma unroll
    for (int j = 0; j < 2; ++j) acc[i][j] = (f32x4){0.f,0.f,0.f,0.f};
  const int am = t >> 2, ak = (t & 3) * 8;
  const int bn = t >> 2, bk = (t & 3) * 8;
  int n = n0 + bn;
  const size_t browbase = ((size_t)b * NPIX + (((n >> 5) << 7) + ((n & 31) << 1))) * CIN;

  uint4 av0 = *(const uint4*)(Wq + (size_t)(m0 + am) * 256 + ak);
  uint4 av1 = *(const uint4*)(Wq + (size_t)(m0 + am) * 256 + 32 + ak);
  uint4 bv0 = *(const uint4*)(h_t + browbase + bk);
  uint4 bv1 = *(const uint4*)(h_t + browbase + 32 + bk);

  for (int k0 = 0; k0 < 256; k0 += 64){
    *(uint4*)&As[am][ak]      = av0;
    *(uint4*)&As[am][32 + ak] = av1;
    *(uint4*)&Bs[bn][bk]      = bv0;
    *(uint4*)&Bs[bn][32 + bk] = bv1;
    __syncthreads();
    if (k0 + 64 < 256){
      av0 = *(const uint4*)(Wq + (size_t)(m0 + am) * 256 + k0 + 64 + ak);
      av1 = *(const uint4*)(Wq + (size_t)(m0 + am) * 256 + k0 + 96 + ak);
      bv0 = *(const uint4*)(h_t + browbase + k0 + 64 + bk);
      bv1 = *(const uint4*)(h_t + browbase + k0 + 96 + bk);
    }
    #pragma unroll
    for (int h = 0; h < 2; ++h){
      short8 af[2], bf[2];
      af[0] = *(const short8*)&As[wm * 32 +      col][h * 32 + quad * 8];
      af[1] = *(const short8*)&As[wm * 32 + 16 + col][h * 32 + quad * 8];
      bf[0] = *(const short8*)&Bs[wn * 32 +      col][h * 32 + quad * 8];
      bf[1] = *(const short8*)&Bs[wn * 32 + 16 + col][h * 32 + quad * 8];
      #pragma unroll
      for (int i = 0; i < 2; ++i)
        #pragma unroll
        for (int j = 0; j < 2; ++j)
          acc[i][j] = __builtin_amdgcn_mfma_f32_16x16x32_bf16(af[i], bf[j], acc[i][j], 0, 0, 0);
    }
    __syncthreads();
  }

  int head = (m0 + wm * 32) >> 5;
  #pragma unroll
  for (int i = 0; i < 2; ++i){
    int d0 = i * 16 + quad * 4;
    #pragma unroll
    for (int j = 0; j < 2; ++j){
      int nn = n0 + wn * 32 + j * 16 + col;
      uint2 pk;
      pk.x = pkbf(acc[i][j][0], acc[i][j][1]);
      pk.y = pkbf(acc[i][j][2], acc[i][j][3]);
      *(uint2*)(qt + ((size_t)(b * HEADS + head) * NQ + nn) * 32 + d0) = pk;
    }
  }
}

// ---------------------------------------------------------------------------
// Fused shortcut+wo GEMM, 64x64 tiles, BK=64 (round-6 verified, unchanged).
// ---------------------------------------------------------------------------
__global__ __launch_bounds__(256) void scwo_gemm(
    const unsigned short* __restrict__ Wf,    // [512][2560]
    const unsigned short* __restrict__ h_t,
    const unsigned short* __restrict__ aot,   // [b][1024][256]
    float* __restrict__ outf){
  const int b  = blockIdx.z;
  const int m0 = blockIdx.y * 64;
  const int n0 = blockIdx.x * 64;
  const int t  = threadIdx.x;
  const int w = t >> 6, lane = t & 63, col = lane & 15, quad = lane >> 4;
  const int wm = w & 1, wn = w >> 1;
  __shared__ unsigned short As[64][72];
  __shared__ unsigned short Bs[64][72];
  f32x4 acc[2][2];
  #pragma unroll
  for (int i = 0; i < 2; ++i)
    #pragma unroll
    for (int j = 0; j < 2; ++j) acc[i][j] = (f32x4){0.f,0.f,0.f,0.f};
  const int am = t >> 2, ak = (t & 3) * 8;
  const int bn = t >> 2, bk = (t & 3) * 8;
  const int n = n0 + bn;
  const int oy = n >> 5, ox = n & 31;
  const size_t aobase = ((size_t)b * NQ + n) * KD;

  auto loadB = [&](int k0) -> uint4 {
    if (k0 < 2304){
      int tap = k0 >> 8;                     // uniform per 32-chunk
      int ky = tap / 3, kx = tap - ky * 3;
      int iy = 2 * oy + ky - 1, ix = 2 * ox + kx - 1;
      if (((unsigned)iy < 64u) && ((unsigned)ix < 64u))
        return *(const uint4*)(h_t + ((size_t)b * NPIX + iy * 64 + ix) * CIN + (k0 & 255) + bk);
      return make_uint4(0,0,0,0);            // conv zero-pad
    }
    return *(const uint4*)(aot + aobase + (k0 - 2304) + bk);
  };

  uint4 av0 = *(const uint4*)(Wf + (size_t)(m0 + am) * WF_K + ak);
  uint4 av1 = *(const uint4*)(Wf + (size_t)(m0 + am) * WF_K + 32 + ak);
  uint4 bv0 = loadB(0);
  uint4 bv1 = loadB(32);

  for (int k0 = 0; k0 < WF_K; k0 += 64){
    *(uint4*)&As[am][ak]      = av0;
    *(uint4*)&As[am][32 + ak] = av1;
    *(uint4*)&Bs[bn][bk]      = bv0;
    *(uint4*)&Bs[bn][32 + bk] = bv1;
    __syncthreads();
    if (k0 + 64 < WF_K){
      av0 = *(const uint4*)(Wf + (size_t)(m0 + am) * WF_K + k0 + 64 + ak);
      av1 = *(const uint4*)(Wf + (size_t)(m0 + am) * WF_K + k0 + 96 + ak);
      bv0 = loadB(k0 + 64);
      bv1 = loadB(k0 + 96);
    }
    #pragma unroll
    for (int h = 0; h < 2; ++h){
      short8 af[2], bf[2];
      af[0] = *(const short8*)&As[wm * 32 +      col][h * 32 + quad * 8];
      af[1] = *(const short8*)&As[wm * 32 + 16 + col][h * 32 + quad * 8];
      bf[0] = *(const short8*)&Bs[wn * 32 +      col][h * 32 + quad * 8];
      bf[1] = *(const short8*)&Bs[wn * 32 + 16 + col][h * 32 + quad * 8];
      #pragma unroll
      for (int i = 0; i < 2; ++i)
        #pragma unroll
        for (int j = 0; j < 2; ++j)
          acc[i][j] = __builtin_amdgcn_mfma_f32_16x16x32_bf16(bf[j], af[i], acc[i][j], 0, 0, 0);
    }
    __syncthreads();
  }

  #pragma unroll
  for (int i = 0; i < 2; ++i){
    int co = m0 + wm * 32 + i * 16 + col;
    #pragma unroll
    for (int j = 0; j < 2; ++j){
      int nb = n0 + wn * 32 + j * 16 + quad * 4;
      float4 o;
      o.x = acc[i][j][0]; o.y = acc[i][j][1];
      o.z = acc[i][j][2]; o.w = acc[i][j][3];
      *(float4*)(outf + ((size_t)(b * COUT + co)) * NQ + nb) = o;
    }
  }
}

// ---------------------------------------------------------------------------
// attn12: occupancy-doubling key-split. Grid 512 = (bh, qg, kh in {0,1});
// each block runs the VERIFIED attn9c body over its 2048-key half (16 steps
// of 128 keys; staging base += kh*65536 shorts -- identical offset for K
// [2048 keys x 32] and V [64 chunks x 1024]). 2 blocks/CU = 4 waves/SIMD
// (vs 2), attacking the latency-boundedness that explains rounds 7/8:
// barrier-halving null, LDS-read-halving negative => chains not pipes bind.
// Epilogue: f32 partials po[kh][bh][1024][32], pl[kh][bh][1024] (no
// normalize); attn_merge combines (round-8-verified merge math).
// ---------------------------------------------------------------------------
__global__ __launch_bounds__(512) void attn12(
    const unsigned short* __restrict__ qt,    // [bh][1024][32] (pre-scaled)
    const unsigned short* __restrict__ ktg,   // [bh][4096][32]
    const unsigned short* __restrict__ vtg,   // [bh][128][32][32] blocked V^T
    float* __restrict__ po,                   // [kh][bh][1024][32] f32
    float* __restrict__ pl){                  // [kh][bh][1024] f32
  __shared__ unsigned short KV[2][8192];      // [buf][K 4096 | V 4096] shorts
  const int bid = blockIdx.x;
  const int xcd = bid & 7, idx = bid >> 3;    // 512 blocks
  const int bh = xcd * 4 + (idx & 3);         // 4 bh per XCD
  const int qg = (idx >> 2) & 7;              // q-group of 128
  const int kh = idx >> 5;                    // key half
  const int t = threadIdx.x;
  const int w = t >> 6, lane = t & 63, col = lane & 15, quad = lane >> 4;
  const int q = (qg * 8 + w) * 16 + col;

  short8 qf = *(const short8*)(qt + ((size_t)bh * NQ + q) * 32 + quad * 8);
  const unsigned short* kb = ktg + (size_t)bh * NK * 32;
  const unsigned short* vb = vtg + (size_t)bh * 128 * 1024;

  // staging addresses (attn9c formulas; step s adds s*4096, half adds 65536)
  const int sg = (w & 3) >> 1, sf = w & 1;
  const size_t ksrc = (size_t)(32 * sg + 16 * sf + col) * 32 + quad * 8;
  const size_t vsrc = (size_t)sg * 1024 + (size_t)(16 * sf + col) * 32 + quad * 8;
  const unsigned short* sb = ((w < 4) ? kb + ksrc : vb + vsrc) + (size_t)kh * 65536;
  unsigned short* ddst = &KV[0][w * 512 + lane * 8 + ((w < 4) ? 0 : 2048)];

  f32x4 O0 = {0.f,0.f,0.f,0.f}, O1 = {0.f,0.f,0.f,0.f}, l4 = {0.f,0.f,0.f,0.f};
  const short8 ones = {0x3F80,0x3F80,0x3F80,0x3F80,0x3F80,0x3F80,0x3F80,0x3F80};

  *(uint4*)ddst          = *(const uint4*)sb;
  *(uint4*)(ddst + 2048) = *(const uint4*)(sb + 2048);
  __syncthreads();

  for (int s = 0; s < 16; ++s){
    const int cur = s & 1;
    uint4 n1, n2;
    if (s + 1 < 16){                          // issue early: latency hides
      size_t soff = (size_t)(s + 1) * 4096;
      n1 = *(const uint4*)(sb + soff);
      n2 = *(const uint4*)(sb + soff + 2048);
    }
    #pragma unroll
    for (int g = 0; g < 4; ++g){
      const unsigned short* Kp = &KV[cur][g * 1024];
      short8 kf0 = *(const short8*)(Kp +       lane * 8);
      short8 kf1 = *(const short8*)(Kp + 512 + lane * 8);
      f32x4 z = {0.f,0.f,0.f,0.f};
      f32x4 slo = __builtin_amdgcn_mfma_f32_16x16x32_bf16(kf0, qf, z, 0, 0, 0);
      f32x4 shi = __builtin_amdgcn_mfma_f32_16x16x32_bf16(kf1, qf, z, 0, 0, 0);

      unsigned x0 = cvtpk(__builtin_amdgcn_exp2f(slo[0]), __builtin_amdgcn_exp2f(slo[1]));
      unsigned x1 = cvtpk(__builtin_amdgcn_exp2f(slo[2]), __builtin_amdgcn_exp2f(slo[3]));
      unsigned y0 = cvtpk(__builtin_amdgcn_exp2f(shi[0]), __builtin_amdgcn_exp2f(shi[1]));
      unsigned y1 = cvtpk(__builtin_amdgcn_exp2f(shi[2]), __builtin_amdgcn_exp2f(shi[3]));
      asm("v_permlane32_swap_b32 %0, %1" : "+v"(x0), "+v"(y0));
      asm("v_permlane32_swap_b32 %0, %1" : "+v"(x1), "+v"(y1));
      asm("v_permlane16_swap_b32 %0, %1" : "+v"(x0), "+v"(y0));
      asm("v_permlane16_swap_b32 %0, %1" : "+v"(x1), "+v"(y1));
      unsigned f[4] = {x0, x1, y0, y1};
      short8 pf;
      memcpy(&pf, f, 16);

      const unsigned short* Vp = &KV[cur][4096 + g * 1024];
      short8 vf0 = *(const short8*)(Vp +       lane * 8);
      short8 vf1 = *(const short8*)(Vp + 512 + lane * 8);
      O0 = __builtin_amdgcn_mfma_f32_16x16x32_bf16(vf0, pf, O0, 0, 0, 0);
      O1 = __builtin_amdgcn_mfma_f32_16x16x32_bf16(vf1, pf, O1, 0, 0, 0);
      l4 = __builtin_amdgcn_mfma_f32_16x16x32_bf16(ones, pf, l4, 0, 0, 0);
    }
    if (s + 1 < 16){
      *(uint4*)(ddst + (size_t)(cur ^ 1) * 8192)        = n1;   // write-late
      *(uint4*)(ddst + 2048 + (size_t)(cur ^ 1) * 8192) = n2;
    }
    __syncthreads();   // all waves done reading cur; next buf visible
  }

  // partial epilogue: raw O,l to global f32 (merge kernel normalizes)
  float* pob = po + (((size_t)(kh * 32 + bh) * NQ + q) * 32);
  *(f32x4*)(pob + quad * 4)      = O0;
  *(f32x4*)(pob + 16 + quad * 4) = O1;
  if (quad == 0) pl[(size_t)(kh * 32 + bh) * NQ + q] = l4[0];
}

// ---------------------------------------------------------------------------
// attn_merge: aot = (po[0]+po[1]) / (pl[0]+pl[1]), bf16. 65536 threads;
// thread g: pair = g>>1 = (bh,q), half = g&1 -> 16 d-elements.
// Merge math identical to round-8-verified attn11 merge (add then normalize).
// ---------------------------------------------------------------------------
__global__ __launch_bounds__(256) void attn_merge(
    const float* __restrict__ po, const float* __restrict__ pl,
    unsigned short* __restrict__ aot){
  const int g = blockIdx.x * 256 + threadIdx.x;
  const int pair = g >> 1, half = g & 1;
  const int bh = pair >> 10, q = pair & 1023;
  const int b = bh >> 3, hd = bh & 7;
  const float* p0 = po + ((size_t)bh * NQ + q) * 32 + half * 16;
  const float* p1 = p0 + (size_t)32 * NQ * 32;
  float l = pl[(size_t)bh * NQ + q] + pl[(size_t)(32 + bh) * NQ + q];
  float inv = 1.0f / l;
  float o[16];
  #pragma unroll
  for (int i = 0; i < 16; i += 4){
    float4 a = *(const float4*)(p0 + i);
    float4 c = *(const float4*)(p1 + i);
    o[i]   = (a.x + c.x) * inv;
    o[i+1] = (a.y + c.y) * inv;
    o[i+2] = (a.z + c.z) * inv;
    o[i+3] = (a.w + c.w) * inv;
  }
  unsigned short* dst = aot + ((size_t)(b * NQ + q)) * KD + hd * 32 + half * 16;
  uint4 pk;
  pk.x = pkbf(o[0],  o[1]);  pk.y = pkbf(o[2],  o[3]);
  pk.z = pkbf(o[4],  o[5]);  pk.w = pkbf(o[6],  o[7]);
  *(uint4*)dst = pk;
  pk.x = pkbf(o[8],  o[9]);  pk.y = pkbf(o[10], o[11]);
  pk.z = pkbf(o[12], o[13]); pk.w = pkbf(o[14], o[15]);
  *(uint4*)(dst + 8) = pk;
}

// ---------------------------------------------------------------------------
extern "C" void kernel_launch(void* const* d_in, const int* in_sizes, int n_in,
                              void* d_out, int out_size, void* d_ws, size_t ws_size,
                              hipStream_t stream){
  const float* x   = (const float*)d_in[0];
  const float* bg  = (const float*)d_in[1];
  const float* bbt = (const float*)d_in[2];
  const float* bm  = (const float*)d_in[3];
  const float* bv  = (const float*)d_in[4];
  const float* wsh = (const float*)d_in[5];
  const float* wq  = (const float*)d_in[6];
  const float* wk  = (const float*)d_in[7];
  const float* wvv = (const float*)d_in[8];
  const float* wo  = (const float*)d_in[9];
  float* out = (float*)d_out;                 // fp32 output

  // workspace (bf16 + f32 partials): ~41 MB
  unsigned short* h_t = (unsigned short*)d_ws;                 // 4*4096*256
  unsigned short* W2  = h_t + (size_t)BB * NPIX * CIN;         // 1,507,328
  unsigned short* qt  = W2  + (WF_E + 3*65536);                // 4*8*1024*32
  unsigned short* aot = qt  + (size_t)BB * HEADS * NQ * 32;    // 4*1024*256
  unsigned short* ktg = aot + (size_t)BB * NQ * KD;            // 4*8*4096*32
  unsigned short* vtg = ktg + (size_t)BB * HEADS * NK * 32;    // 4*8*128*1024
  unsigned short* wend = vtg + (size_t)BB * HEADS * 32 * NK;
  float* po = (float*)wend;                                    // 2*32*1024*32
  float* pl = po + (size_t)2 * 32 * NQ * 32;                   // 2*32*1024
  size_t need = ((size_t)(wend - h_t)) * 2
              + ((size_t)2 * 32 * NQ * 32 + (size_t)2 * 32 * NQ) * 4;
  if (ws_size < need) return;

  unsigned short* Wf   = W2;                   // [512][2560] = wsh|wo fused
  unsigned short* wq2  = W2 + WF_E;
  unsigned short* wkv2 = wq2 + 65536;          // [wk2;wv2] = [512][256]

  prep_all<<<dim3(1088), dim3(256), 0, stream>>>(x, bg, bbt, bm, bv,
                                                 wsh, wq, wk, wvv, wo, h_t, W2);
  qkv_gemm<<<dim3(32, 10, 4), dim3(256), 0, stream>>>(wkv2, wq2, h_t, ktg, vtg, qt);
  attn12<<<dim3(512), dim3(512), 0, stream>>>(qt, ktg, vtg, po, pl);
  attn_merge<<<dim3(256), dim3(256), 0, stream>>>(po, pl, aot);
  scwo_gemm<<<dim3(16, 8, 4), dim3(256), 0, stream>>>(Wf, h_t, aot, out);
}